// Round 4
// baseline (272.084 us; speedup 1.0000x reference)
//
#include <hip/hip_runtime.h>
#include <hip/hip_bf16.h>

typedef unsigned short u16;
typedef unsigned int u32;
typedef __attribute__((ext_vector_type(8))) __bf16 bf16x8;
typedef __attribute__((ext_vector_type(4))) float f32x4;
typedef __attribute__((ext_vector_type(8))) short short8;

#define EPSF 2.220446049250313e-16f

__device__ __forceinline__ u16 f2bf(float f) {
    u32 u = __float_as_uint(f);
    return (u16)((u + 0x7FFFu + ((u >> 16) & 1u)) >> 16);  // RNE
}

__device__ __forceinline__ void gll16(const void* g, void* l) {
    __builtin_amdgcn_global_load_lds(
        (const __attribute__((address_space(1))) unsigned int*)g,
        (__attribute__((address_space(3))) unsigned int*)l, 16, 0, 0);
}

#define MEMFENCE asm volatile("" ::: "memory")
#define BAR() do { MEMFENCE; __builtin_amdgcn_s_barrier(); MEMFENCE; } while (0)
#define VMWAIT(N) do { asm volatile("s_waitcnt vmcnt(" #N ")" ::: "memory"); \
                       __builtin_amdgcn_sched_barrier(0); } while (0)

// ---------- kernel 1: PONO center + L2 normalize + transposed bf16 write ----------
// single pass; fp32 LDS retention with ODD row stride (261) so both the
// transpose write (stride-2-row) and read (lane=pixel) are ~conflict-free.
// grid 512 (b = blk>>7, 32 px each), 512 threads.
__global__ __launch_bounds__(512) void prep_kernel(
    const float* __restrict__ X, const float* __restrict__ Y,
    u16* __restrict__ XnT, u16* __restrict__ YnT)
{
    const int b  = blockIdx.x >> 7;
    const int p0 = (blockIdx.x & 127) << 5;
    const int t  = threadIdx.x;
    const int w  = t >> 6, l = t & 63;
    const size_t base = (size_t)b * 256 * 4096 + p0;

    __shared__ float TXf[32 * 261], TYf[32 * 261];
    __shared__ float part[8][16][8];
    __shared__ float meanL[32], rxL[32], ryL[32];

    const int pxp = t & 15;   // pixel pair: px = 2*pxp, 2*pxp+1
    const int cs  = t >> 4;   // 0..31 -> channels cs*8 .. cs*8+7
    float sx0=0,sxx0=0,sy0=0,syy0=0, sx1=0,sxx1=0,sy1=0,syy1=0;
    #pragma unroll
    for (int k = 0; k < 8; ++k) {
        int c = cs * 8 + k;
        size_t off = base + (size_t)c * 4096 + pxp * 2;
        float2 vx = *(const float2*)(X + off);
        float2 vy = *(const float2*)(Y + off);
        TXf[(pxp*2) * 261 + c] = vx.x; TXf[(pxp*2+1) * 261 + c] = vx.y;
        TYf[(pxp*2) * 261 + c] = vy.x; TYf[(pxp*2+1) * 261 + c] = vy.y;
        sx0 += vx.x; sxx0 += vx.x*vx.x; sy0 += vy.x; syy0 += vy.x*vy.x;
        sx1 += vx.y; sxx1 += vx.y*vx.y; sy1 += vy.y; syy1 += vy.y*vy.y;
    }
    #pragma unroll
    for (int sh = 16; sh <= 32; sh <<= 1) {
        sx0 += __shfl_xor(sx0, sh, 64); sxx0 += __shfl_xor(sxx0, sh, 64);
        sy0 += __shfl_xor(sy0, sh, 64); syy0 += __shfl_xor(syy0, sh, 64);
        sx1 += __shfl_xor(sx1, sh, 64); sxx1 += __shfl_xor(sxx1, sh, 64);
        sy1 += __shfl_xor(sy1, sh, 64); syy1 += __shfl_xor(syy1, sh, 64);
    }
    if (l < 16) {
        part[w][l][0]=sx0; part[w][l][1]=sxx0; part[w][l][2]=sy0; part[w][l][3]=syy0;
        part[w][l][4]=sx1; part[w][l][5]=sxx1; part[w][l][6]=sy1; part[w][l][7]=syy1;
    }
    __syncthreads();
    if (t < 32) {
        const int pp = t >> 1, sub = (t & 1) * 4;
        float Sx=0, Sxx=0, Sy=0, Syy=0;
        #pragma unroll
        for (int ww = 0; ww < 8; ++ww) {
            Sx += part[ww][pp][sub+0]; Sxx += part[ww][pp][sub+1];
            Sy += part[ww][pp][sub+2]; Syy += part[ww][pp][sub+3];
        }
        float m = Sy * (1.f / 256.f);
        float ssx = fmaxf(Sxx - 2.f*m*Sx + 256.f*m*m, 0.f);
        float ssy = fmaxf(Syy - 2.f*m*Sy + 256.f*m*m, 0.f);
        meanL[t] = m;
        rxL[t] = 1.f / (sqrtf(ssx) + EPSF);
        ryL[t] = 1.f / (sqrtf(ssy) + EPSF);
    }
    __syncthreads();
    // store phase: px = t&31 (conflict-free: 261*px mod 32 spans all banks),
    // c-block = t>>5 (16 channels each)
    {
        const int px = t & 31, cb = t >> 5;
        const float m = meanL[px], rxv = rxL[px], ryv = ryL[px];
        size_t ob = ((size_t)b * 4096 + p0 + px) * 256 + cb * 16;
        #pragma unroll
        for (int h = 0; h < 2; ++h) {
            short8 hx, hy;
            #pragma unroll
            for (int k = 0; k < 8; ++k) {
                int c = cb * 16 + h * 8 + k;
                hx[k] = (short)f2bf((TXf[px * 261 + c] - m) * rxv);
                hy[k] = (short)f2bf((TYf[px * 261 + c] - m) * ryv);
            }
            *(short8*)(XnT + ob + h * 8) = hx;
            *(short8*)(YnT + ob + h * 8) = hy;
        }
    }
}

// ---------- kernels 2/3: A-in-registers streaming GEMM ----------
// 256 thr (4 waves), block = 128 i-rows x 1024 j-cols. Wave owns 32 rows:
// A-frags (16 bf16x8 = 64 VGPR) loaded once from global. B streamed through
// LDS dbuf (2 x 32KB), 16 j-subtiles of 64, counted vmcnt(8), 2 bar/subtile.
template <int PASS>
__global__ __launch_bounds__(256, 2) void cx_pass(
    const u16* __restrict__ XnT, const u16* __restrict__ YnT,
    const float* __restrict__ smax, float* __restrict__ partials)
{
    __shared__ u16 Bs[2][16384];   // 64 KB total

    const int t = threadIdx.x;
    const int w = t >> 6;
    const int l = t & 63;
    const int l15 = l & 15, g = l >> 4;

    // XCD swizzle: batch b pinned to XCD pair {2b, 2b+1}
    const int id   = blockIdx.x;
    const int xcd  = id & 7;
    const int slot = id >> 3;                    // 0..63
    const int b    = xcd >> 1;
    const int tid2 = ((xcd & 1) << 6) | slot;    // 0..127
    const int it = tid2 >> 2, jr = tid2 & 3;
    const int i0 = it << 7;      // 128 rows
    const int j0 = jr << 10;     // 1024 cols

    const u16* Ab = XnT + ((size_t)b * 4096 + i0) * 256;
    const u16* Bb = YnT + ((size_t)b * 4096 + j0) * 256;

    // ---- A fragments in registers: rows i0 + w*32 + fm*16 + l15, k-slice g ----
    bf16x8 a[2][8];
    #pragma unroll
    for (int fm = 0; fm < 2; ++fm)
        #pragma unroll
        for (int ks = 0; ks < 8; ++ks)
            a[fm][ks] = *(const bf16x8*)((const char*)Ab +
                (size_t)(w * 32 + fm * 16 + l15) * 512 + ks * 64 + g * 16);

    // per-row softmax params (PASS1): row = w*32 + fm*16 + g*4 + r
    float moff[2][4], itau[2][4];
    if (PASS == 1) {
        #pragma unroll
        for (int fm = 0; fm < 2; ++fm)
            #pragma unroll
            for (int r = 0; r < 4; ++r) {
                float m = smax[(size_t)b * 4096 + i0 + w * 32 + fm * 16 + g * 4 + r];
                float itv = 1.44269504f / (0.1f * (1.001f - m));  // log2e / tau
                itau[fm][r] = itv;
                moff[fm][r] = m * itv;
            }
    }

    // staging: 8 gll16/thread per 64-row subtile; pre-swizzled source chunk
    const int srow0 = t >> 5;                      // row within 8-row group
    const int gch   = ((t & 31) ^ srow0);          // inverse-swizzled 16B chunk
    auto stage = [&](int d, int st) {
        const u16* Bt = Bb + (size_t)st * 64 * 256;
        #pragma unroll
        for (int q = 0; q < 8; ++q)
            gll16(Bt + (size_t)(q * 8 + srow0) * 256 + gch * 8,
                  &Bs[d][q * 2048 + w * 512]);
    };

    float racc[2][4];
    #pragma unroll
    for (int fm = 0; fm < 2; ++fm)
        #pragma unroll
        for (int r = 0; r < 4; ++r) racc[fm][r] = (PASS == 0) ? -2.0f : 0.0f;

    const int bswz = (l15 & 7) << 4;  // row&7 == l15&7 for row = fn*16+l15

    // prologue: stage subtile 0
    stage(0, 0);

    #pragma unroll
    for (int s = 0; s < 16; ++s) {
        if (s < 15) stage((s + 1) & 1, s + 1);
        if (s < 15) { VMWAIT(8); } else { VMWAIT(0); }
        BAR();
        // ---- compute subtile s from Bs[s&1] ----
        {
            const char* bp = (const char*)&Bs[s & 1][0];
            f32x4 acc[2][4] = {};
            #pragma unroll
            for (int ks = 0; ks < 8; ++ks) {
                bf16x8 bf[4];
                #pragma unroll
                for (int fn = 0; fn < 4; ++fn) {
                    int row = fn * 16 + l15;
                    bf[fn] = *(const bf16x8*)(bp + row * 512 +
                                              ((ks * 64 + g * 16) ^ bswz));
                }
                __builtin_amdgcn_s_setprio(1);
                #pragma unroll
                for (int fm = 0; fm < 2; ++fm)
                    #pragma unroll
                    for (int fn = 0; fn < 4; ++fn)
                        acc[fm][fn] = __builtin_amdgcn_mfma_f32_16x16x32_bf16(
                            a[fm][ks], bf[fn], acc[fm][fn], 0, 0, 0);
                __builtin_amdgcn_s_setprio(0);
            }
            // fold subtile into running max / exp-sum (registers only)
            #pragma unroll
            for (int fm = 0; fm < 2; ++fm)
                #pragma unroll
                for (int r = 0; r < 4; ++r) {
                    if (PASS == 0) {
                        float v = fmaxf(fmaxf(acc[fm][0][r], acc[fm][1][r]),
                                        fmaxf(acc[fm][2][r], acc[fm][3][r]));
                        racc[fm][r] = fmaxf(racc[fm][r], v);
                    } else {
                        float e0 = exp2f(fmaf(acc[fm][0][r], itau[fm][r], -moff[fm][r]));
                        float e1 = exp2f(fmaf(acc[fm][1][r], itau[fm][r], -moff[fm][r]));
                        float e2 = exp2f(fmaf(acc[fm][2][r], itau[fm][r], -moff[fm][r]));
                        float e3 = exp2f(fmaf(acc[fm][3][r], itau[fm][r], -moff[fm][r]));
                        racc[fm][r] += (e0 + e1) + (e2 + e3);
                    }
                }
        }
        BAR();
    }

    // ---- lane-reduce over the 16 cols (l15) and store partial ----
    #pragma unroll
    for (int fm = 0; fm < 2; ++fm)
        #pragma unroll
        for (int r = 0; r < 4; ++r) {
            float v = racc[fm][r];
            if (PASS == 0) {
                v = fmaxf(v, __shfl_xor(v, 1, 64));
                v = fmaxf(v, __shfl_xor(v, 2, 64));
                v = fmaxf(v, __shfl_xor(v, 4, 64));
                v = fmaxf(v, __shfl_xor(v, 8, 64));
            } else {
                v += __shfl_xor(v, 1, 64);
                v += __shfl_xor(v, 2, 64);
                v += __shfl_xor(v, 4, 64);
                v += __shfl_xor(v, 8, 64);
            }
            if (l15 == 0)
                partials[((size_t)b * 4096 + i0 + w * 32 + fm * 16 + g * 4 + r) * 4 + jr] = v;
        }
}

// ---------- row reductions over the 4 partial slots ----------
template <int OP>  // 0 = max, 1 = sum
__global__ __launch_bounds__(256) void reduce_rows(
    const float* __restrict__ part, float* __restrict__ outv)
{
    const int row = blockIdx.x * 256 + threadIdx.x;
    float4 v = *(const float4*)(part + (size_t)row * 4);
    outv[row] = (OP == 0)
        ? fmaxf(fmaxf(v.x, v.y), fmaxf(v.z, v.w))
        : (v.x + v.y) + (v.z + v.w);
}

// ---------- final reduction ----------
__global__ __launch_bounds__(1024) void final_kernel(
    const float* __restrict__ Stot, float* __restrict__ out)
{
    __shared__ float red[16];
    const int t = threadIdx.x;
    float loss = 0.f;
    for (int b = 0; b < 4; ++b) {
        float s = 0.f;
        #pragma unroll
        for (int k = 0; k < 4; ++k)
            s += 1.0f / Stot[(size_t)b * 4096 + k * 1024 + t];
        #pragma unroll
        for (int sh = 1; sh <= 32; sh <<= 1) s += __shfl_xor(s, sh, 64);
        if ((t & 63) == 0) red[t >> 6] = s;
        __syncthreads();
        if (t == 0) {
            float tot = 0.f;
            #pragma unroll
            for (int k = 0; k < 16; ++k) tot += red[k];
            loss += -logf(tot * (1.f / 4096.f));
        }
        __syncthreads();
    }
    if (t == 0) out[0] = loss * 0.25f;
}

extern "C" void kernel_launch(void* const* d_in, const int* in_sizes, int n_in,
                              void* d_out, int out_size, void* d_ws, size_t ws_size,
                              hipStream_t stream)
{
    const float* X = (const float*)d_in[0];
    const float* Y = (const float*)d_in[1];
    char* ws = (char*)d_ws;
    u16* XnT = (u16*)(ws);                                   // 8 MB
    u16* YnT = (u16*)(ws + (8u << 20));                      // 8 MB
    float* partials = (float*)(ws + (16u << 20));            // 256 KB [16384][4]
    float* smax = (float*)(ws + (17u << 20));                // 64 KB
    float* Stot = (float*)(ws + (17u << 20) + (64u << 10));  // 64 KB
    float* out = (float*)d_out;

    hipLaunchKernelGGL(prep_kernel, dim3(512), dim3(512), 0, stream,
                       X, Y, XnT, YnT);
    hipLaunchKernelGGL((cx_pass<0>), dim3(512), dim3(256), 0, stream,
                       XnT, YnT, smax, partials);
    hipLaunchKernelGGL((reduce_rows<0>), dim3(64), dim3(256), 0, stream,
                       partials, smax);
    hipLaunchKernelGGL((cx_pass<1>), dim3(512), dim3(256), 0, stream,
                       XnT, YnT, smax, partials);
    hipLaunchKernelGGL((reduce_rows<1>), dim3(64), dim3(256), 0, stream,
                       partials, Stot);
    hipLaunchKernelGGL(final_kernel, dim3(1), dim3(1024), 0, stream, Stot, out);
}

// Round 5
// 174.309 us; speedup vs baseline: 1.5609x; 1.5609x over previous
//
#include <hip/hip_runtime.h>
#include <hip/hip_bf16.h>

typedef unsigned short u16;
typedef unsigned int u32;
typedef __attribute__((ext_vector_type(8))) __bf16 bf16x8;
typedef __attribute__((ext_vector_type(4))) float f32x4;
typedef __attribute__((ext_vector_type(8))) short short8;

#define EPSF 2.220446049250313e-16f

__device__ __forceinline__ u16 f2bf(float f) {
    u32 u = __float_as_uint(f);
    return (u16)((u + 0x7FFFu + ((u >> 16) & 1u)) >> 16);  // RNE
}

__device__ __forceinline__ void gll16(const void* g, void* l) {
    __builtin_amdgcn_global_load_lds(
        (const __attribute__((address_space(1))) unsigned int*)g,
        (__attribute__((address_space(3))) unsigned int*)l, 16, 0, 0);
}

#define MEMFENCE asm volatile("" ::: "memory")
#define BAR() do { MEMFENCE; __builtin_amdgcn_s_barrier(); MEMFENCE; } while (0)
#define VMWAIT(N) do { asm volatile("s_waitcnt vmcnt(" #N ")" ::: "memory"); \
                       __builtin_amdgcn_sched_barrier(0); } while (0)

// ---------- kernel 1: PONO center + L2 normalize + transposed bf16 write ----------
// Two phases (Y then X) share one 64px x 256c fp32 LDS tile (66.8 KB).
// Loads fully coalesced (64 lanes x 4B = 256B/instr); stats via Sx/Sxx.
// grid 256 (b = blk>>6, 64 px each), 256 threads.
__global__ __launch_bounds__(256) void prep_kernel(
    const float* __restrict__ X, const float* __restrict__ Y,
    u16* __restrict__ XnT, u16* __restrict__ YnT)
{
    const int b  = blockIdx.x >> 6;
    const int p0 = (blockIdx.x & 63) << 6;
    const int t  = threadIdx.x;
    const int w  = t >> 6, l = t & 63;
    const size_t base = (size_t)b * 256 * 4096 + p0;

    __shared__ float T[64 * 261];          // [px][c], stride 261 (odd -> no conflicts)
    __shared__ float pS[4][64], pSS[4][64];
    __shared__ float meanL[64], rnL[64];

    const int ch = t & 31, pxs = t >> 5;   // write-phase coords

    // ================= phase Y =================
    {
        float s1 = 0.f, s2 = 0.f;
        #pragma unroll 8
        for (int rep = 0; rep < 64; ++rep) {
            int c = rep * 4 + w;
            float v = Y[base + (size_t)c * 4096 + l];
            T[l * 261 + c] = v;
            s1 += v; s2 += v * v;
        }
        pS[w][l] = s1; pSS[w][l] = s2;
        __syncthreads();
        if (t < 64) {
            float Sy  = pS[0][t] + pS[1][t] + pS[2][t] + pS[3][t];
            float Syy = pSS[0][t] + pSS[1][t] + pSS[2][t] + pSS[3][t];
            float m = Sy * (1.f / 256.f);
            float ss = fmaxf(Syy - m * Sy, 0.f);   // Syy - 2m*Sy + 256m^2, 256m==Sy
            meanL[t] = m;
            rnL[t] = 1.f / (sqrtf(ss) + EPSF);
        }
        __syncthreads();
        #pragma unroll
        for (int rep = 0; rep < 8; ++rep) {
            int px = rep * 8 + pxs;
            float m = meanL[px], rn = rnL[px];
            short8 h;
            #pragma unroll
            for (int k = 0; k < 8; ++k)
                h[k] = (short)f2bf((T[px * 261 + ch * 8 + k] - m) * rn);
            *(short8*)(YnT + ((size_t)b * 4096 + p0 + px) * 256 + ch * 8) = h;
        }
        __syncthreads();
    }
    // ================= phase X =================
    {
        float s1 = 0.f, s2 = 0.f;
        #pragma unroll 8
        for (int rep = 0; rep < 64; ++rep) {
            int c = rep * 4 + w;
            float v = X[base + (size_t)c * 4096 + l];
            T[l * 261 + c] = v;
            s1 += v; s2 += v * v;
        }
        pS[w][l] = s1; pSS[w][l] = s2;
        __syncthreads();
        if (t < 64) {
            float Sx  = pS[0][t] + pS[1][t] + pS[2][t] + pS[3][t];
            float Sxx = pSS[0][t] + pSS[1][t] + pSS[2][t] + pSS[3][t];
            float m = meanL[t];
            float ss = fmaxf(Sxx - 2.f * m * Sx + 256.f * m * m, 0.f);
            rnL[t] = 1.f / (sqrtf(ss) + EPSF);
        }
        __syncthreads();
        #pragma unroll
        for (int rep = 0; rep < 8; ++rep) {
            int px = rep * 8 + pxs;
            float m = meanL[px], rn = rnL[px];
            short8 h;
            #pragma unroll
            for (int k = 0; k < 8; ++k)
                h[k] = (short)f2bf((T[px * 261 + ch * 8 + k] - m) * rn);
            *(short8*)(XnT + ((size_t)b * 4096 + p0 + px) * 256 + ch * 8) = h;
        }
    }
}

// ---------- kernels 2/3: A-in-registers streaming GEMM (spill-safe) ----------
// 256 thr, 4 waves (2wr x 2wc). Block = 64 i-rows x 1024 j. Wave = 32r x 32c
// per subtile. A: 16 bf16x8 regs (full K=256). B: 64j x 256K subtiles (32KB)
// double-buffered, dynamic ping-pong loop, counted vmcnt(8).
template <int PASS>
__global__ __launch_bounds__(256, 4) void cx_pass(
    const u16* __restrict__ XnT, const u16* __restrict__ YnT,
    const float* __restrict__ partIn, float* __restrict__ partOut)
{
    __shared__ u16 B0[16384];      // 32 KB
    __shared__ u16 B1[16384];      // 32 KB
    __shared__ float smxL[64];
    __shared__ float redL[64][2];

    const int t = threadIdx.x;
    const int w = t >> 6, l = t & 63;
    const int l15 = l & 15, g = l >> 4;
    const int wr = w >> 1, wc = w & 1;

    // XCD swizzle: batch b pinned to XCD pair {2b, 2b+1}
    const int id = blockIdx.x;
    const int xcd = id & 7, slot = id >> 3;      // slot 0..127
    const int b = xcd >> 1;
    const int sub = ((xcd & 1) << 7) | slot;     // 0..255
    const int it = sub >> 2, jr = sub & 3;
    const int i0 = it << 6;       // 64 rows
    const int j0 = jr << 10;      // 1024 cols

    const u16* Ab = XnT + ((size_t)b * 4096 + i0) * 256;
    const u16* Bb = YnT + ((size_t)b * 4096 + j0) * 256;

    // ---- A into registers: rows wr*32 + fm*16 + l15, K = ks*32 + g*8 ----
    bf16x8 a[2][8];
    #pragma unroll
    for (int fm = 0; fm < 2; ++fm)
        #pragma unroll
        for (int ks = 0; ks < 8; ++ks)
            a[fm][ks] = *(const bf16x8*)((const char*)Ab +
                (wr * 32 + fm * 16 + l15) * 512 + ks * 64 + g * 16);

    // ---- PASS1: row max from pass-0 partials; per-lane itau/moff ----
    if (PASS == 1) {
        if (t < 64) {
            float4 v = *(const float4*)(partIn + ((size_t)b * 4096 + i0 + t) * 4);
            smxL[t] = fmaxf(fmaxf(v.x, v.y), fmaxf(v.z, v.w));
        }
        __syncthreads();
    }
    float itau[2][4], moff[2][4];
    if (PASS == 1) {
        #pragma unroll
        for (int fm = 0; fm < 2; ++fm)
            #pragma unroll
            for (int r = 0; r < 4; ++r) {
                float m = smxL[wr * 32 + fm * 16 + g * 4 + r];
                float iv = 14.4269504089f / (1.001f - m);  // log2e / (0.1*(1.001-m))
                itau[fm][r] = iv;
                moff[fm][r] = m * iv;
            }
    }

    float racc[2][4];
    #pragma unroll
    for (int fm = 0; fm < 2; ++fm)
        #pragma unroll
        for (int r = 0; r < 4; ++r) racc[fm][r] = (PASS == 0) ? -2.0f : 0.0f;

    // staging: 8 gll16/thread per 32KB subtile; verified swizzled mapping
    const int srow0 = t >> 5;
    const int gch = (t & 31) ^ srow0;
    auto stage = [&](u16* dst, const u16* src) {
        #pragma unroll
        for (int q = 0; q < 8; ++q)
            gll16(src + (q * 8 + srow0) * 256 + gch * 8, dst + q * 2048 + w * 512);
    };

    const int swz = (l15 & 7) << 4;
    auto compute = [&](const u16* buf) {
        f32x4 acc[2][2] = {};
        #pragma unroll
        for (int ks = 0; ks < 8; ++ks) {
            const int kb = ks * 64 + g * 16;
            bf16x8 bf0 = *(const bf16x8*)((const char*)buf + (wc * 32 + l15) * 512 + (kb ^ swz));
            bf16x8 bf1 = *(const bf16x8*)((const char*)buf + (wc * 32 + 16 + l15) * 512 + (kb ^ swz));
            __builtin_amdgcn_s_setprio(1);
            acc[0][0] = __builtin_amdgcn_mfma_f32_16x16x32_bf16(a[0][ks], bf0, acc[0][0], 0, 0, 0);
            acc[0][1] = __builtin_amdgcn_mfma_f32_16x16x32_bf16(a[0][ks], bf1, acc[0][1], 0, 0, 0);
            acc[1][0] = __builtin_amdgcn_mfma_f32_16x16x32_bf16(a[1][ks], bf0, acc[1][0], 0, 0, 0);
            acc[1][1] = __builtin_amdgcn_mfma_f32_16x16x32_bf16(a[1][ks], bf1, acc[1][1], 0, 0, 0);
            __builtin_amdgcn_s_setprio(0);
        }
        #pragma unroll
        for (int fm = 0; fm < 2; ++fm)
            #pragma unroll
            for (int r = 0; r < 4; ++r) {
                if (PASS == 0) {
                    racc[fm][r] = fmaxf(racc[fm][r], fmaxf(acc[fm][0][r], acc[fm][1][r]));
                } else {
                    racc[fm][r] += exp2f(fmaf(acc[fm][0][r], itau[fm][r], -moff[fm][r]))
                                 + exp2f(fmaf(acc[fm][1][r], itau[fm][r], -moff[fm][r]));
                }
            }
    };

    // ---- pipeline over 16 subtiles (64 j each), ping-pong, counted vmcnt ----
    const u16* src = Bb;
    stage(B0, src); src += 16384;
    #pragma unroll 1
    for (int s2 = 0; s2 < 8; ++s2) {
        stage(B1, src); src += 16384;
        VMWAIT(8); BAR();
        compute(B0);
        BAR();
        if (s2 < 7) {
            stage(B0, src); src += 16384;
            VMWAIT(8); BAR();
        } else {
            VMWAIT(0); BAR();
        }
        compute(B1);
        BAR();
    }

    // ---- epilogue: shfl-reduce over 16 cols, cross-wc combine in LDS ----
    #pragma unroll
    for (int fm = 0; fm < 2; ++fm)
        #pragma unroll
        for (int r = 0; r < 4; ++r) {
            float v = racc[fm][r];
            if (PASS == 0) {
                v = fmaxf(v, __shfl_xor(v, 1, 64));
                v = fmaxf(v, __shfl_xor(v, 2, 64));
                v = fmaxf(v, __shfl_xor(v, 4, 64));
                v = fmaxf(v, __shfl_xor(v, 8, 64));
            } else {
                v += __shfl_xor(v, 1, 64);
                v += __shfl_xor(v, 2, 64);
                v += __shfl_xor(v, 4, 64);
                v += __shfl_xor(v, 8, 64);
            }
            if (l15 == 0) redL[wr * 32 + fm * 16 + g * 4 + r][wc] = v;
        }
    __syncthreads();
    if (t < 64) {
        float res = (PASS == 0) ? fmaxf(redL[t][0], redL[t][1])
                                : redL[t][0] + redL[t][1];
        partOut[((size_t)b * 4096 + i0 + t) * 4 + jr] = res;
    }
}

// ---------- kernel 4: per-row CX = 1/Ssum, partial sums per block ----------
__global__ __launch_bounds__(256) void csum_kernel(
    const float* __restrict__ p1, float* __restrict__ csum)
{
    __shared__ float rr[4];
    const int t = threadIdx.x;
    const int row = blockIdx.x * 256 + t;
    float4 v = *(const float4*)(p1 + (size_t)row * 4);
    float cx = 1.0f / ((v.x + v.y) + (v.z + v.w));
    #pragma unroll
    for (int sh = 1; sh <= 32; sh <<= 1) cx += __shfl_xor(cx, sh, 64);
    if ((t & 63) == 0) rr[t >> 6] = cx;
    __syncthreads();
    if (t == 0) csum[blockIdx.x] = rr[0] + rr[1] + rr[2] + rr[3];
}

// ---------- kernel 5: final loss ----------
__global__ __launch_bounds__(64) void final_kernel(
    const float* __restrict__ csum, float* __restrict__ out)
{
    __shared__ float rb[4];
    const int t = threadIdx.x;   // 64 threads; csum[64], b = t>>4
    float v = csum[t];
    v += __shfl_xor(v, 1, 64);
    v += __shfl_xor(v, 2, 64);
    v += __shfl_xor(v, 4, 64);
    v += __shfl_xor(v, 8, 64);
    if ((t & 15) == 0) rb[t >> 4] = v;
    __syncthreads();
    if (t == 0) {
        float loss = 0.f;
        #pragma unroll
        for (int bb = 0; bb < 4; ++bb)
            loss += -logf(rb[bb] * (1.f / 4096.f));
        out[0] = loss * 0.25f;
    }
}

extern "C" void kernel_launch(void* const* d_in, const int* in_sizes, int n_in,
                              void* d_out, int out_size, void* d_ws, size_t ws_size,
                              hipStream_t stream)
{
    const float* X = (const float*)d_in[0];
    const float* Y = (const float*)d_in[1];
    char* ws = (char*)d_ws;
    u16* XnT = (u16*)(ws);                                    // 8 MB
    u16* YnT = (u16*)(ws + (8u << 20));                       // 8 MB
    float* part0 = (float*)(ws + (16u << 20));                // 256 KB [16384][4]
    float* part1 = (float*)(ws + (16u << 20) + (256u << 10)); // 256 KB
    float* csum  = (float*)(ws + (16u << 20) + (512u << 10)); // 256 B
    float* out = (float*)d_out;

    hipLaunchKernelGGL(prep_kernel, dim3(256), dim3(256), 0, stream,
                       X, Y, XnT, YnT);
    hipLaunchKernelGGL((cx_pass<0>), dim3(1024), dim3(256), 0, stream,
                       XnT, YnT, part0, part0);
    hipLaunchKernelGGL((cx_pass<1>), dim3(1024), dim3(256), 0, stream,
                       XnT, YnT, part0, part1);
    hipLaunchKernelGGL(csum_kernel, dim3(64), dim3(256), 0, stream,
                       part1, csum);
    hipLaunchKernelGGL(final_kernel, dim3(1), dim3(64), 0, stream,
                       csum, out);
}

// Round 7
// 169.463 us; speedup vs baseline: 1.6056x; 1.0286x over previous
//
#include <hip/hip_runtime.h>
#include <hip/hip_bf16.h>

typedef unsigned short u16;
typedef unsigned int u32;
typedef __attribute__((ext_vector_type(8))) __bf16 bf16x8;
typedef __attribute__((ext_vector_type(4))) float f32x4;
typedef __attribute__((ext_vector_type(8))) short short8;

#define EPSF 2.220446049250313e-16f

__device__ __forceinline__ u16 f2bf(float f) {
    u32 u = __float_as_uint(f);
    return (u16)((u + 0x7FFFu + ((u >> 16) & 1u)) >> 16);  // RNE
}

// ---------- kernel 1: PONO center + L2 normalize + FRAGMENT-PACK bf16 write ----
// Pack layout (per batch, 2^20 u16): frag[(fb*8 + ks)*64 + g*16 + p][e]
// where fb = row>>4, lane l = g*16 + (row&15) holds k = ks*32 + g*8 + e.
// A wave later reads one MFMA operand as ONE coalesced 1KB dwordx4 load.
// Each thread owns (px, 16 consecutive k) -> its two short8 writes ARE the
// pack entries: no transpose, no big LDS. grid 1024 (b = blk>>8), 256 thr.
__global__ __launch_bounds__(256) void prep_kernel(
    const float* __restrict__ X, const float* __restrict__ Y,
    u16* __restrict__ Xp, u16* __restrict__ Yp)
{
    const int blk = blockIdx.x;
    const int b = blk >> 8;
    const int fbase = blk & 255;            // row-block of 16 = frag block
    const int t = threadIdx.x;
    const int px = t & 15, cg = t >> 4;     // cg in [0,16): k-range cg*16..+15
    const int l = t & 63, wv = t >> 6;
    const size_t base = (size_t)b * 256 * 4096 + (fbase << 4) + px;

    __shared__ float pA[4][16], pB[4][16];
    __shared__ float meanL[16], rnL[16];

    const int ks = cg >> 1;
    const int g0 = (cg & 1) << 1;
    const size_t pbase = (size_t)b << 20;
    const size_t addr0 = pbase + ((size_t)(fbase * 8 + ks) * 64 + g0 * 16 + px) * 8;

    float vals[16];

    // ================= phase Y =================
    {
        float s1 = 0.f, s2 = 0.f;
        #pragma unroll
        for (int k = 0; k < 16; ++k) {
            float v = Y[base + (size_t)(cg * 16 + k) * 4096];
            vals[k] = v; s1 += v; s2 += v * v;
        }
        s1 += __shfl_xor(s1, 16, 64); s2 += __shfl_xor(s2, 16, 64);
        s1 += __shfl_xor(s1, 32, 64); s2 += __shfl_xor(s2, 32, 64);
        if (l < 16) { pA[wv][l] = s1; pB[wv][l] = s2; }
        __syncthreads();
        if (t < 16) {
            float Sy = pA[0][t] + pA[1][t] + pA[2][t] + pA[3][t];
            float Syy = pB[0][t] + pB[1][t] + pB[2][t] + pB[3][t];
            float m = Sy * (1.f / 256.f);
            meanL[t] = m;
            rnL[t] = 1.f / (sqrtf(fmaxf(Syy - m * Sy, 0.f)) + EPSF);
        }
        __syncthreads();
        float m = meanL[px], rn = rnL[px];
        short8 h0, h1;
        #pragma unroll
        for (int k = 0; k < 8; ++k) {
            h0[k] = (short)f2bf((vals[k] - m) * rn);
            h1[k] = (short)f2bf((vals[8 + k] - m) * rn);
        }
        *(short8*)(Yp + addr0) = h0;
        *(short8*)(Yp + addr0 + 128) = h1;   // g0+1 block: +16 lanes * 8
        __syncthreads();
    }
    // ================= phase X (uses meanY) =================
    {
        float s1 = 0.f, s2 = 0.f;
        #pragma unroll
        for (int k = 0; k < 16; ++k) {
            float v = X[base + (size_t)(cg * 16 + k) * 4096];
            vals[k] = v; s1 += v; s2 += v * v;
        }
        s1 += __shfl_xor(s1, 16, 64); s2 += __shfl_xor(s2, 16, 64);
        s1 += __shfl_xor(s1, 32, 64); s2 += __shfl_xor(s2, 32, 64);
        if (l < 16) { pA[wv][l] = s1; pB[wv][l] = s2; }
        __syncthreads();
        if (t < 16) {
            float Sx = pA[0][t] + pA[1][t] + pA[2][t] + pA[3][t];
            float Sxx = pB[0][t] + pB[1][t] + pB[2][t] + pB[3][t];
            float m = meanL[t];
            rnL[t] = 1.f / (sqrtf(fmaxf(Sxx - 2.f * m * Sx + 256.f * m * m, 0.f)) + EPSF);
        }
        __syncthreads();
        float m = meanL[px], rn = rnL[px];
        short8 h0, h1;
        #pragma unroll
        for (int k = 0; k < 8; ++k) {
            h0[k] = (short)f2bf((vals[k] - m) * rn);
            h1[k] = (short)f2bf((vals[8 + k] - m) * rn);
        }
        *(short8*)(Xp + addr0) = h0;
        *(short8*)(Xp + addr0 + 128) = h1;
    }
}

// ---------- kernels 2/3: pure-register GEMM, zero LDS in hot loop ----------
// 256 thr, 4 waves. Block = 64 i (A regs a[4][8], full K=256) x 2048 j.
// Wave wc handles jt = jh*128 + wc + 4u, u in [0,32). Each B fragment is one
// coalesced 1KB dwordx4 from the L2-resident pack. No barriers, no LDS.
template <int PASS>
__global__ __launch_bounds__(256, 2) void cx_pass(
    const u16* __restrict__ Xp, const u16* __restrict__ Yp,
    const float* __restrict__ partIn, float* __restrict__ partOut)
{
    __shared__ float smxL[64];
    __shared__ float redL[64][4];

    const int t = threadIdx.x;
    const int w = t >> 6, l = t & 63;
    const int l15 = l & 15, g = l >> 4;
    const int wc = w;

    // XCD swizzle: batch b pinned to XCD pair {2b, 2b+1}
    const int id = blockIdx.x;
    const int xcd = id & 7, slot = id >> 3;      // slot 0..63
    const int b = xcd >> 1;
    const int it2 = ((xcd & 1) << 5) | (slot >> 1);  // 0..63
    const int jh = slot & 1;
    const int i0 = it2 << 6;                     // 64 rows

    const size_t pb = (size_t)b << 20;

    if (PASS == 1) {
        if (t < 64) {
            float2 v = ((const float2*)partIn)[(size_t)b * 4096 + i0 + t];
            smxL[t] = fmaxf(v.x, v.y);
        }
        __syncthreads();
    }

    // ---- A fragments (coalesced 1KB loads): frag block fb = i0/16 + fm ----
    bf16x8 a[4][8];
    {
        const u16* Apl = Xp + pb + (size_t)l * 8;
        #pragma unroll
        for (int fm = 0; fm < 4; ++fm)
            #pragma unroll
            for (int ks = 0; ks < 8; ++ks)
                a[fm][ks] = *(const bf16x8*)(Apl + (size_t)(((i0 >> 4) + fm) * 8 + ks) * 512);
    }

    float mo[4][4], it_[4][4];
    if (PASS == 1) {
        #pragma unroll
        for (int fm = 0; fm < 4; ++fm)
            #pragma unroll
            for (int r = 0; r < 4; ++r) {
                float m = smxL[fm * 16 + g * 4 + r];
                float iv = 14.4269504089f / (1.001f - m);  // log2e/(0.1*(1.001-m))
                it_[fm][r] = iv;
                mo[fm][r] = m * iv;
            }
    }

    float racc[4][4];
    #pragma unroll
    for (int fm = 0; fm < 4; ++fm)
        #pragma unroll
        for (int r = 0; r < 4; ++r) racc[fm][r] = (PASS == 0) ? -2.0f : 0.0f;

    // ---- hot loop: 32 j-tiles per wave, 8 loads + 32 MFMA each ----
    const u16* Bpl = Yp + pb + (size_t)l * 8 + (size_t)(jh * 128 + wc) * 4096;
    #pragma unroll 1
    for (int u = 0; u < 32; ++u) {
        const u16* bp = Bpl + (size_t)u * 16384;   // += 4 jt
        f32x4 acc0 = {}, acc1 = {}, acc2 = {}, acc3 = {};
        #pragma unroll
        for (int ks = 0; ks < 8; ++ks) {
            bf16x8 bv = *(const bf16x8*)(bp + (ks << 9));
            acc0 = __builtin_amdgcn_mfma_f32_16x16x32_bf16(a[0][ks], bv, acc0, 0, 0, 0);
            acc1 = __builtin_amdgcn_mfma_f32_16x16x32_bf16(a[1][ks], bv, acc1, 0, 0, 0);
            acc2 = __builtin_amdgcn_mfma_f32_16x16x32_bf16(a[2][ks], bv, acc2, 0, 0, 0);
            acc3 = __builtin_amdgcn_mfma_f32_16x16x32_bf16(a[3][ks], bv, acc3, 0, 0, 0);
        }
        if (PASS == 0) {
            #pragma unroll
            for (int r = 0; r < 4; ++r) {
                racc[0][r] = fmaxf(racc[0][r], acc0[r]);
                racc[1][r] = fmaxf(racc[1][r], acc1[r]);
                racc[2][r] = fmaxf(racc[2][r], acc2[r]);
                racc[3][r] = fmaxf(racc[3][r], acc3[r]);
            }
        } else {
            #pragma unroll
            for (int r = 0; r < 4; ++r) {
                racc[0][r] += exp2f(__builtin_fmaf(acc0[r], it_[0][r], -mo[0][r]));
                racc[1][r] += exp2f(__builtin_fmaf(acc1[r], it_[1][r], -mo[1][r]));
                racc[2][r] += exp2f(__builtin_fmaf(acc2[r], it_[2][r], -mo[2][r]));
                racc[3][r] += exp2f(__builtin_fmaf(acc3[r], it_[3][r], -mo[3][r]));
            }
        }
    }

    // ---- epilogue: shfl-reduce over 16 cols, cross-wave combine in LDS ----
    #pragma unroll
    for (int fm = 0; fm < 4; ++fm)
        #pragma unroll
        for (int r = 0; r < 4; ++r) {
            float v = racc[fm][r];
            if (PASS == 0) {
                v = fmaxf(v, __shfl_xor(v, 1, 64));
                v = fmaxf(v, __shfl_xor(v, 2, 64));
                v = fmaxf(v, __shfl_xor(v, 4, 64));
                v = fmaxf(v, __shfl_xor(v, 8, 64));
            } else {
                v += __shfl_xor(v, 1, 64);
                v += __shfl_xor(v, 2, 64);
                v += __shfl_xor(v, 4, 64);
                v += __shfl_xor(v, 8, 64);
            }
            if (l15 == 0) redL[fm * 16 + g * 4 + r][wc] = v;
        }
    __syncthreads();
    if (t < 64) {
        float4 vv = *(const float4*)&redL[t][0];
        float res = (PASS == 0)
            ? fmaxf(fmaxf(vv.x, vv.y), fmaxf(vv.z, vv.w))
            : (vv.x + vv.y) + (vv.z + vv.w);
        partOut[((size_t)b * 4096 + i0 + t) * 2 + jh] = res;
    }
}

// ---------- kernel 4: per-row CX = 1/Ssum, partial sums per block ----------
__global__ __launch_bounds__(256) void csum_kernel(
    const float* __restrict__ p1, float* __restrict__ csum)
{
    __shared__ float rr[4];
    const int t = threadIdx.x;
    const int row = blockIdx.x * 256 + t;
    float2 v = ((const float2*)p1)[row];
    float cx = 1.0f / (v.x + v.y);
    #pragma unroll
    for (int sh = 1; sh <= 32; sh <<= 1) cx += __shfl_xor(cx, sh, 64);
    if ((t & 63) == 0) rr[t >> 6] = cx;
    __syncthreads();
    if (t == 0) csum[blockIdx.x] = rr[0] + rr[1] + rr[2] + rr[3];
}

// ---------- kernel 5: final loss ----------
__global__ __launch_bounds__(64) void final_kernel(
    const float* __restrict__ csum, float* __restrict__ out)
{
    __shared__ float rb[4];
    const int t = threadIdx.x;   // csum[64], b = t>>4
    float v = csum[t];
    v += __shfl_xor(v, 1, 64);
    v += __shfl_xor(v, 2, 64);
    v += __shfl_xor(v, 4, 64);
    v += __shfl_xor(v, 8, 64);
    if ((t & 15) == 0) rb[t >> 4] = v;
    __syncthreads();
    if (t == 0) {
        float loss = 0.f;
        #pragma unroll
        for (int bb = 0; bb < 4; ++bb)
            loss += -logf(rb[bb] * (1.f / 4096.f));
        out[0] = loss * 0.25f;
    }
}

extern "C" void kernel_launch(void* const* d_in, const int* in_sizes, int n_in,
                              void* d_out, int out_size, void* d_ws, size_t ws_size,
                              hipStream_t stream)
{
    const float* X = (const float*)d_in[0];
    const float* Y = (const float*)d_in[1];
    char* ws = (char*)d_ws;
    u16* Xp = (u16*)(ws);                                     // 8 MB frag-pack
    u16* Yp = (u16*)(ws + (8u << 20));                        // 8 MB frag-pack
    float* part0 = (float*)(ws + (16u << 20));                // 128 KB [16384][2]
    float* part1 = (float*)(ws + (16u << 20) + (128u << 10)); // 128 KB
    float* csum  = (float*)(ws + (16u << 20) + (256u << 10)); // 256 B
    float* out = (float*)d_out;

    hipLaunchKernelGGL(prep_kernel, dim3(1024), dim3(256), 0, stream,
                       X, Y, Xp, Yp);
    hipLaunchKernelGGL((cx_pass<0>), dim3(512), dim3(256), 0, stream,
                       Xp, Yp, part0, part0);
    hipLaunchKernelGGL((cx_pass<1>), dim3(512), dim3(256), 0, stream,
                       Xp, Yp, part0, part1);
    hipLaunchKernelGGL(csum_kernel, dim3(64), dim3(256), 0, stream,
                       part1, csum);
    hipLaunchKernelGGL(final_kernel, dim3(1), dim3(64), 0, stream,
                       csum, out);
}

// Round 8
// 168.545 us; speedup vs baseline: 1.6143x; 1.0054x over previous
//
#include <hip/hip_runtime.h>
#include <hip/hip_bf16.h>

typedef unsigned short u16;
typedef unsigned int u32;
typedef __attribute__((ext_vector_type(8))) __bf16 bf16x8;
typedef __attribute__((ext_vector_type(4))) float f32x4;
typedef __attribute__((ext_vector_type(8))) short short8;

#define EPSF 2.220446049250313e-16f

__device__ __forceinline__ u16 f2bf(float f) {
    u32 u = __float_as_uint(f);
    return (u16)((u + 0x7FFFu + ((u >> 16) & 1u)) >> 16);  // RNE
}

// ---------- kernel 1: PONO center + L2 normalize + FRAGMENT-PACK bf16 write ----
// Pack layout (per batch, 2^20 u16): elem addr = ((fb*8 + ks)*64 + g*16 + p)*8 + e
// for matrix row = fb*16 + p, k = ks*32 + g*8 + e  (verified R7, absmax 0).
// Thread owns (px, 16 consecutive k) -> its two short8 writes ARE pack entries:
// no LDS transpose. Loads fully coalesced (fixed c => 32 consecutive px/lane-half).
// grid 512 (b = blk>>7, 32 px each), 512 threads (pxl = t&31, cg = t>>5 in [0,16)).
__global__ __launch_bounds__(512) void prep_kernel(
    const float* __restrict__ X, const float* __restrict__ Y,
    u16* __restrict__ Xp, u16* __restrict__ Yp)
{
    const int blk = blockIdx.x;
    const int b = blk >> 7;
    const int p0 = (blk & 127) << 5;
    const int t = threadIdx.x;
    const int pxl = t & 31, cg = t >> 5;
    const size_t base = (size_t)b * 256 * 4096 + p0 + pxl;

    __shared__ float pS[16][32], pSS[16][32];
    __shared__ float meanL[32], rnL[32];

    const size_t pbase = (size_t)b << 20;
    const int fb = (p0 + pxl) >> 4;
    const int ks = cg >> 1, g0 = (cg & 1) << 1;
    const size_t addr0 = pbase + ((size_t)(fb * 8 + ks) * 64 + g0 * 16 + (pxl & 15)) * 8;

    float vals[16];

    // ================= phase Y =================
    {
        float s1 = 0.f, s2 = 0.f;
        #pragma unroll
        for (int e = 0; e < 16; ++e) {
            float v = Y[base + (size_t)(cg * 16 + e) * 4096];
            vals[e] = v; s1 += v; s2 += v * v;
        }
        pS[cg][pxl] = s1; pSS[cg][pxl] = s2;
        __syncthreads();
        if (t < 32) {
            float Sy = 0.f, Syy = 0.f;
            #pragma unroll
            for (int c = 0; c < 16; ++c) { Sy += pS[c][t]; Syy += pSS[c][t]; }
            float m = Sy * (1.f / 256.f);
            meanL[t] = m;
            rnL[t] = 1.f / (sqrtf(fmaxf(Syy - m * Sy, 0.f)) + EPSF);
        }
        __syncthreads();
        const float m = meanL[pxl], rn = rnL[pxl];
        short8 h0, h1;
        #pragma unroll
        for (int e = 0; e < 8; ++e) {
            h0[e] = (short)f2bf((vals[e] - m) * rn);
            h1[e] = (short)f2bf((vals[8 + e] - m) * rn);
        }
        *(short8*)(Yp + addr0) = h0;
        *(short8*)(Yp + addr0 + 128) = h1;   // g0+1: +16 lanes * 8 elems
        __syncthreads();                      // pS reuse fence
    }
    // ================= phase X (centered by meanY) =================
    {
        float s1 = 0.f, s2 = 0.f;
        #pragma unroll
        for (int e = 0; e < 16; ++e) {
            float v = X[base + (size_t)(cg * 16 + e) * 4096];
            vals[e] = v; s1 += v; s2 += v * v;
        }
        pS[cg][pxl] = s1; pSS[cg][pxl] = s2;
        __syncthreads();
        if (t < 32) {
            float Sx = 0.f, Sxx = 0.f;
            #pragma unroll
            for (int c = 0; c < 16; ++c) { Sx += pS[c][t]; Sxx += pSS[c][t]; }
            float m = meanL[t];
            rnL[t] = 1.f / (sqrtf(fmaxf(Sxx - 2.f * m * Sx + 256.f * m * m, 0.f)) + EPSF);
        }
        __syncthreads();
        const float m = meanL[pxl], rn = rnL[pxl];
        short8 h0, h1;
        #pragma unroll
        for (int e = 0; e < 8; ++e) {
            h0[e] = (short)f2bf((vals[e] - m) * rn);
            h1[e] = (short)f2bf((vals[8 + e] - m) * rn);
        }
        *(short8*)(Xp + addr0) = h0;
        *(short8*)(Xp + addr0 + 128) = h1;
    }
}

// ---------- kernels 2/3: pure-register GEMM, A guaranteed resident ----------
// 256 thr, 4 waves. Block = 32 i (a[2][8] = 64 VGPR, fits under the 128 cap)
// x 1024 j. 4 blocks/CU (launch_bounds 256,4) -> 4 waves/SIMD latency hiding.
// Wave wc: jt = jq*64 + wc + 4u, u<16. B frag = one coalesced 1KB load, L2-hot.
template <int PASS>
__global__ __launch_bounds__(256, 4) void cx_pass(
    const u16* __restrict__ Xp, const u16* __restrict__ Yp,
    const float* __restrict__ partIn, float* __restrict__ partOut)
{
    __shared__ float smxL[32];
    __shared__ float redL[32][4];

    const int t = threadIdx.x;
    const int w = t >> 6, l = t & 63;
    const int l15 = l & 15, g = l >> 4;
    const int wc = w;

    // XCD swizzle: batch b pinned to XCD pair {2b, 2b+1}
    const int id = blockIdx.x;
    const int xcd = id & 7, slot = id >> 3;          // slot 0..255
    const int b = xcd >> 1;
    const int tl = ((xcd & 1) << 8) | slot;          // 0..511
    const int it = tl >> 2, jq = tl & 3;
    const int i0 = it << 5;                          // 32 rows

    const size_t pb = (size_t)b << 20;

    if (PASS == 1) {
        if (t < 32) {
            float4 v = ((const float4*)partIn)[(size_t)b * 4096 + i0 + t];
            smxL[t] = fmaxf(fmaxf(v.x, v.y), fmaxf(v.z, v.w));
        }
        __syncthreads();
    }

    // ---- A fragments (16 coalesced 1KB loads = 64 VGPR, stays resident) ----
    bf16x8 a[2][8];
    {
        const u16* Apl = Xp + pb + (size_t)l * 8;
        #pragma unroll
        for (int fm = 0; fm < 2; ++fm)
            #pragma unroll
            for (int ks = 0; ks < 8; ++ks)
                a[fm][ks] = *(const bf16x8*)(Apl + (size_t)(((i0 >> 4) + fm) * 8 + ks) * 512);
    }

    float mo[2][4], it_[2][4];
    if (PASS == 1) {
        #pragma unroll
        for (int fm = 0; fm < 2; ++fm)
            #pragma unroll
            for (int r = 0; r < 4; ++r) {
                float m = smxL[fm * 16 + g * 4 + r];
                float iv = 14.4269504089f / (1.001f - m);  // log2e/(0.1*(1.001-m))
                it_[fm][r] = iv;
                mo[fm][r] = m * iv;
            }
    }

    float racc[2][4];
    #pragma unroll
    for (int fm = 0; fm < 2; ++fm)
        #pragma unroll
        for (int r = 0; r < 4; ++r) racc[fm][r] = (PASS == 0) ? -2.0f : 0.0f;

    // ---- hot loop: 16 j-tiles per wave, 8 loads + 16 MFMA each ----
    const u16* Bpl = Yp + pb + (size_t)l * 8 + (size_t)(jq * 64 + wc) * 4096;
    #pragma unroll 1
    for (int u = 0; u < 16; ++u) {
        const u16* bp = Bpl + (size_t)u * 16384;   // advance 4 jt
        f32x4 acc0 = {}, acc1 = {};
        #pragma unroll
        for (int ks = 0; ks < 8; ++ks) {
            bf16x8 bv = *(const bf16x8*)(bp + (ks << 9));
            acc0 = __builtin_amdgcn_mfma_f32_16x16x32_bf16(a[0][ks], bv, acc0, 0, 0, 0);
            acc1 = __builtin_amdgcn_mfma_f32_16x16x32_bf16(a[1][ks], bv, acc1, 0, 0, 0);
        }
        if (PASS == 0) {
            #pragma unroll
            for (int r = 0; r < 4; ++r) {
                racc[0][r] = fmaxf(racc[0][r], acc0[r]);
                racc[1][r] = fmaxf(racc[1][r], acc1[r]);
            }
        } else {
            #pragma unroll
            for (int r = 0; r < 4; ++r) {
                racc[0][r] += exp2f(__builtin_fmaf(acc0[r], it_[0][r], -mo[0][r]));
                racc[1][r] += exp2f(__builtin_fmaf(acc1[r], it_[1][r], -mo[1][r]));
            }
        }
    }

    // ---- epilogue: shfl-reduce over 16 cols, cross-wave combine in LDS ----
    #pragma unroll
    for (int fm = 0; fm < 2; ++fm)
        #pragma unroll
        for (int r = 0; r < 4; ++r) {
            float v = racc[fm][r];
            if (PASS == 0) {
                v = fmaxf(v, __shfl_xor(v, 1, 64));
                v = fmaxf(v, __shfl_xor(v, 2, 64));
                v = fmaxf(v, __shfl_xor(v, 4, 64));
                v = fmaxf(v, __shfl_xor(v, 8, 64));
            } else {
                v += __shfl_xor(v, 1, 64);
                v += __shfl_xor(v, 2, 64);
                v += __shfl_xor(v, 4, 64);
                v += __shfl_xor(v, 8, 64);
            }
            if (l15 == 0) redL[fm * 16 + g * 4 + r][wc] = v;
        }
    __syncthreads();
    if (t < 32) {
        float4 vv = *(const float4*)&redL[t][0];
        float res = (PASS == 0)
            ? fmaxf(fmaxf(vv.x, vv.y), fmaxf(vv.z, vv.w))
            : (vv.x + vv.y) + (vv.z + vv.w);
        partOut[((size_t)b * 4096 + i0 + t) * 4 + jq] = res;
    }
}

// ---------- kernel 4: per-row CX = 1/Ssum, partial sums per block ----------
__global__ __launch_bounds__(256) void csum_kernel(
    const float* __restrict__ p1, float* __restrict__ csum)
{
    __shared__ float rr[4];
    const int t = threadIdx.x;
    const int row = blockIdx.x * 256 + t;
    float4 v = ((const float4*)p1)[row];
    float cx = 1.0f / ((v.x + v.y) + (v.z + v.w));
    #pragma unroll
    for (int sh = 1; sh <= 32; sh <<= 1) cx += __shfl_xor(cx, sh, 64);
    if ((t & 63) == 0) rr[t >> 6] = cx;
    __syncthreads();
    if (t == 0) csum[blockIdx.x] = rr[0] + rr[1] + rr[2] + rr[3];
}

// ---------- kernel 5: final loss ----------
__global__ __launch_bounds__(64) void final_kernel(
    const float* __restrict__ csum, float* __restrict__ out)
{
    __shared__ float rb[4];
    const int t = threadIdx.x;   // csum[64], b = t>>4
    float v = csum[t];
    v += __shfl_xor(v, 1, 64);
    v += __shfl_xor(v, 2, 64);
    v += __shfl_xor(v, 4, 64);
    v += __shfl_xor(v, 8, 64);
    if ((t & 15) == 0) rb[t >> 4] = v;
    __syncthreads();
    if (t == 0) {
        float loss = 0.f;
        #pragma unroll
        for (int bb = 0; bb < 4; ++bb)
            loss += -logf(rb[bb] * (1.f / 4096.f));
        out[0] = loss * 0.25f;
    }
}

extern "C" void kernel_launch(void* const* d_in, const int* in_sizes, int n_in,
                              void* d_out, int out_size, void* d_ws, size_t ws_size,
                              hipStream_t stream)
{
    const float* X = (const float*)d_in[0];
    const float* Y = (const float*)d_in[1];
    char* ws = (char*)d_ws;
    u16* Xp = (u16*)(ws);                                     // 8 MB frag-pack
    u16* Yp = (u16*)(ws + (8u << 20));                        // 8 MB frag-pack
    float* part0 = (float*)(ws + (16u << 20));                // 256 KB [16384][4]
    float* part1 = (float*)(ws + (16u << 20) + (256u << 10)); // 256 KB
    float* csum  = (float*)(ws + (16u << 20) + (512u << 10)); // 256 B
    float* out = (float*)d_out;

    hipLaunchKernelGGL(prep_kernel, dim3(512), dim3(512), 0, stream,
                       X, Y, Xp, Yp);
    hipLaunchKernelGGL((cx_pass<0>), dim3(2048), dim3(256), 0, stream,
                       Xp, Yp, part0, part0);
    hipLaunchKernelGGL((cx_pass<1>), dim3(2048), dim3(256), 0, stream,
                       Xp, Yp, part0, part1);
    hipLaunchKernelGGL(csum_kernel, dim3(64), dim3(256), 0, stream,
                       part1, csum);
    hipLaunchKernelGGL(final_kernel, dim3(1), dim3(64), 0, stream,
                       csum, out);
}